// Round 2
// baseline (1027.264 us; speedup 1.0000x reference)
//
#include <hip/hip_runtime.h>
#include <cstdint>

// Problem constants
#define BB 2
#define CC 128
#define IH 800
#define IW 640
#define NN 8192
#define HWp (IH * IW)        // 512000 pixels per batch
#define CE 130               // C + 2 (features + nb x,y)
#define WSL (CE * CC)        // 16640 floats per weight slice [e][o]
#define VPB 16               // vertices per block in fused_all

// Staggered LDS address for f[e][v] (v in 0..15): scatter writes land 4-way
// max on banks; rows stay 16B-aligned for float4 broadcast reads.
// bank(FADDR(e,0)) walks {0,16,4,20,8,24,12,28}; HWC scatter (e=4l+j) -> 4l
// mod 32 -> 8 banks/32 lanes = 4-way.
#define FADDR(e, v) (((e) << 4) + ((((e) >> 2)) << 2) + (v))
#define FSZ (FADDR(129, 15) + 1)   // 2208 floats

// ---------------- bilinear helpers ----------------

__device__ __forceinline__ void coords(float gx, float gy, int& xs, int& ys,
                                       float& ax, float& ay) {
  // match reference: clip(((g+1)*0.5)*(dim-1), 0, dim-1); shifting the segment
  // start to min(floor, dim-2) with ax in [0,1] reproduces border padding
  // exactly (at x==dim-1: ax=1 selects the border texel).
  float x = (gx + 1.0f) * 0.5f * (float)(IW - 1);
  x = fminf(fmaxf(x, 0.0f), (float)(IW - 1));
  float y = (gy + 1.0f) * 0.5f * (float)(IH - 1);
  y = fminf(fmaxf(y, 0.0f), (float)(IH - 1));
  xs = min((int)x, IW - 2);
  ys = min((int)y, IH - 2);
  ax = x - (float)xs;
  ay = y - (float)ys;
}

// HWC gather, split into issue (loads) / finish (blend) so 4 samples' loads
// can all be in flight per wave. Lane l<32 covers channels 4l..4l+3 at x=xs;
// lanes 32..63 cover the same channels at x=xs+1 (contiguous 1KB per row).
struct GatIssue {
  float4 v0, v1;
  float ax, ay;
};

__device__ __forceinline__ GatIssue gat_issue(const float* __restrict__ imgT,
                                              int b, float gx, float gy, int l) {
  int xs, ys; float ax, ay;
  coords(gx, gy, xs, ys, ax, ay);
  const float* base = imgT + ((size_t)b * HWp + (size_t)ys * IW + xs) * CC;
  GatIssue g;
  g.v0 = *(const float4*)(base + l * 4);
  g.v1 = *(const float4*)(base + (size_t)IW * CC + l * 4);
  g.ax = ax; g.ay = ay;
  return g;
}

__device__ __forceinline__ float4 gat_finish(const GatIssue& g, int l) {
  float my = 1.0f - g.ay, mx = 1.0f - g.ax;
  float4 vy;
  vy.x = g.v0.x * my + g.v1.x * g.ay;
  vy.y = g.v0.y * my + g.v1.y * g.ay;
  vy.z = g.v0.z * my + g.v1.z * g.ay;
  vy.w = g.v0.w * my + g.v1.w * g.ay;
  float4 vo;
  vo.x = __shfl_xor(vy.x, 32, 64);
  vo.y = __shfl_xor(vy.y, 32, 64);
  vo.z = __shfl_xor(vy.z, 32, 64);
  vo.w = __shfl_xor(vy.w, 32, 64);
  float4 r;
  if (l < 32) {
    r.x = vy.x * mx + vo.x * g.ax;
    r.y = vy.y * mx + vo.y * g.ax;
    r.z = vy.z * mx + vo.z * g.ax;
    r.w = vy.w * mx + vo.w * g.ax;
  } else {
    r.x = vo.x * mx + vy.x * g.ax;
    r.y = vo.y * mx + vy.y * g.ax;
    r.z = vo.z * mx + vy.z * g.ax;
    r.w = vo.w * mx + vy.w * g.ax;
  }
  return r;
}

// CHW (fallback) gather of one channel
__device__ __forceinline__ float gat1_chw(const float* __restrict__ img, int b,
                                          int c, int xs, int ys, float ax, float ay) {
  const float* p = img + ((size_t)(b * CC + c) * IH + ys) * IW + xs;
  float v00 = p[0], v01 = p[1], v10 = p[IW], v11 = p[IW + 1];
  float my = 1.0f - ay, mx = 1.0f - ax;
  return (v00 * mx + v01 * ax) * my + (v10 * mx + v11 * ax) * ay;
}

// ---------------- weight folding ----------------

// blocks 0..127: Wd[c][e] = sum_c2 W_d2[c][c2]*W_d1[c2][e]; bdf[c]
// blocks 128..255: Wcc[o][e] = sum_c2 W_c2[o][c2]*W_c1[c2][e]; bcc[o]
__global__ void prep1(const float* __restrict__ W_d1, const float* __restrict__ b_d1,
                      const float* __restrict__ W_d2, const float* __restrict__ b_d2,
                      const float* __restrict__ W_c1, const float* __restrict__ b_c1,
                      const float* __restrict__ W_c2, const float* __restrict__ b_c2,
                      float* __restrict__ Wd, float* __restrict__ bdf,
                      float* __restrict__ Wcc, float* __restrict__ bcc) {
  int id = blockIdx.x;
  int e = threadIdx.x;  // 0..129
  if (id < 128) {
    int c = id;
    float acc = 0.0f;
    for (int c2 = 0; c2 < 128; ++c2)
      acc = fmaf(W_d2[c * 128 + c2], W_d1[c2 * CE + e], acc);
    Wd[c * CE + e] = acc;
    if (e == 0) {
      float bb = b_d2[c];
      for (int c2 = 0; c2 < 128; ++c2) bb = fmaf(W_d2[c * 128 + c2], b_d1[c2], bb);
      bdf[c] = bb;
    }
  } else {
    int o = id - 128;
    float acc = 0.0f;
    for (int c2 = 0; c2 < 128; ++c2)
      acc = fmaf(W_c2[o * 128 + c2], W_c1[c2 * CE + e], acc);
    Wcc[o * CE + e] = acc;
    if (e == 0) {
      float bb = b_c2[o];
      for (int c2 = 0; c2 < 128; ++c2) bb = fmaf(W_c2[o * 128 + c2], b_c1[c2], bb);
      bcc[o] = bb;
    }
  }
}

// grid 130 (e), block 128 (o):
// combo[o,k,e] = sum_c W_sn[o,c,k]*Wd[c,e]  -> Wnb[k-1][e][o], k=1..8
// Wcen[e][o] = Wcc[o][e] - sum_{k=1..8} combo
// btot[o] = bcc[o] + sum_c (sum_{k=0..8} W_sn[o,c,k])*bdf[c] + b_sn[o]
__global__ void prep2(const float* __restrict__ W_sn, const float* __restrict__ b_sn,
                      const float* __restrict__ Wd, const float* __restrict__ bdf,
                      const float* __restrict__ Wcc, const float* __restrict__ bcc,
                      float* __restrict__ Wcen, float* __restrict__ Wnb,
                      float* __restrict__ btot) {
  int eb = blockIdx.x;   // 0..129
  int o = threadIdx.x;   // 0..127
  float acc[9] = {0, 0, 0, 0, 0, 0, 0, 0, 0};
  float bacc = 0.0f;
  for (int c = 0; c < 128; ++c) {
    float wd = Wd[c * CE + eb];
    float bd = bdf[c];
    const float* sn = W_sn + (size_t)o * 1152 + c * 9;
    float ssum = 0.0f;
#pragma unroll
    for (int k = 0; k < 9; ++k) {
      float s = sn[k];
      acc[k] = fmaf(s, wd, acc[k]);
      ssum += s;
    }
    bacc = fmaf(ssum, bd, bacc);
  }
  float sum18 = 0.0f;
#pragma unroll
  for (int k = 1; k < 9; ++k) {
    Wnb[(size_t)(k - 1) * WSL + eb * 128 + o] = acc[k];
    sum18 += acc[k];
  }
  Wcen[eb * 128 + o] = Wcc[o * CE + eb] - sum18;
  if (eb == 0) btot[o] = bcc[o] + bacc + b_sn[o];
}

// ---------------- transpose (B,C,H,W) -> (B,HW,C) ----------------
// 64px x 128ch tile. float4 global loads AND stores (16B/lane). LDS stride 69
// floats: store phase 2-way (free), load phase 4-way (1.58x) — LDS far from
// the bottleneck; HBM is.

__global__ __launch_bounds__(256) void transpose_k(const float* __restrict__ img,
                                                   float* __restrict__ imgT) {
  __shared__ float tile[128][69];
  int b = blockIdx.y;
  size_t p0 = (size_t)blockIdx.x * 64;
  int t = threadIdx.x;
  int pq = t & 15, cr = t >> 4;          // read: float4 along pixels
  float4 vr[8];
#pragma unroll
  for (int i = 0; i < 8; ++i) {
    int c = cr + (i << 4);
    vr[i] = *(const float4*)(img + (size_t)(b * CC + c) * HWp + p0 + pq * 4);
  }
#pragma unroll
  for (int i = 0; i < 8; ++i) {
    int c = cr + (i << 4);
    tile[c][pq * 4 + 0] = vr[i].x;
    tile[c][pq * 4 + 1] = vr[i].y;
    tile[c][pq * 4 + 2] = vr[i].z;
    tile[c][pq * 4 + 3] = vr[i].w;
  }
  __syncthreads();
  int c4 = (t & 31) << 2, pw = t >> 5;   // write: float4 along channels
#pragma unroll
  for (int i = 0; i < 8; ++i) {
    int p = pw + (i << 3);
    float4 v;
    v.x = tile[c4 + 0][p];
    v.y = tile[c4 + 1][p];
    v.z = tile[c4 + 2][p];
    v.w = tile[c4 + 3][p];
    *(float4*)(imgT + ((size_t)b * HWp + p0 + p) * CC + c4) = v;
  }
}

// ---------------- fully fused: center + offsets + gathers + folded GEMM ----

template <bool HWC>
__global__ __launch_bounds__(256) void fused_all(
    const float* __restrict__ imgp, const float* __restrict__ verts,
    const float* __restrict__ W_sd, const float* __restrict__ b_sd,
    const float* __restrict__ Wcen, const float* __restrict__ Wnb,
    const float* __restrict__ btot, float* __restrict__ out) {
  __shared__ __align__(16) float f[FSZ];   // f[e][v], staggered
  __shared__ float sdl[VPB][18];
  __shared__ float nbc[VPB][16];           // 8 neighbors x (x,y)
  __shared__ float red[128][17];           // padded: 2-way only
  int t = threadIdx.x;
  int o = t & 127, hs = t >> 7;
  int e0 = hs * 65;                        // halves split the e-range
  int v0 = blockIdx.x * VPB;
  int wv = t >> 6, l = t & 63;
  float acc[VPB] = {};

  // ---- center gather (slice 0): wave wv samples vertices 4wv..4wv+3 ----
  if constexpr (HWC) {
    GatIssue g[4];
    float gxy[4][2];
#pragma unroll
    for (int s = 0; s < 4; ++s) {
      int vid = v0 + wv * 4 + s, b = vid >> 13;
      float gx = verts[vid * 2], gy = verts[vid * 2 + 1];
      gxy[s][0] = gx; gxy[s][1] = gy;
      g[s] = gat_issue(imgp, b, gx, gy, l);
    }
#pragma unroll
    for (int s = 0; s < 4; ++s) {
      int v = wv * 4 + s;
      float4 r = gat_finish(g[s], l);
      if (l < 32) {
        f[FADDR(4 * l + 0, v)] = r.x;
        f[FADDR(4 * l + 1, v)] = r.y;
        f[FADDR(4 * l + 2, v)] = r.z;
        f[FADDR(4 * l + 3, v)] = r.w;
      }
      if (l == 32) { f[FADDR(128, v)] = gxy[s][0]; f[FADDR(129, v)] = gxy[s][1]; }
    }
  } else {
    for (int s = 0; s < 4; ++s) {
      int v = wv * 4 + s, vid = v0 + v, b = vid >> 13;
      float gx = verts[vid * 2], gy = verts[vid * 2 + 1];
      int xs, ys; float ax, ay;
      coords(gx, gy, xs, ys, ax, ay);
      f[FADDR(l, v)] = gat1_chw(imgp, b, l, xs, ys, ax, ay);
      f[FADDR(l + 64, v)] = gat1_chw(imgp, b, l + 64, xs, ys, ax, ay);
      if (l == 0) { f[FADDR(128, v)] = gx; f[FADDR(129, v)] = gy; }
    }
  }
  __syncthreads();

  // ---- offset GEMV: sdl[v][oo] = b_sd[oo] + sum_c W_sd[oo,c]*feat[v][c] ----
  for (int idx = t; idx < VPB * 18; idx += 256) {
    int v = idx / 18, oo = idx - v * 18;
    float a = b_sd[oo];
    for (int c = 0; c < 128; ++c)
      a = fmaf(W_sd[oo * 128 + c], f[FADDR(c, v)], a);
    sdl[v][oo] = a;
  }

  // ---- slice-0 GEMM (reads f; independent of sdl) ----
  {
    const float* Ws = Wcen;
    for (int e = e0; e < e0 + 65; ++e) {
      float w = Ws[e * 128 + o];
      const float4* fp = (const float4*)&f[FADDR(e, 0)];
      float4 fa = fp[0], fb = fp[1], fc = fp[2], fd = fp[3];
      acc[0]  = fmaf(fa.x, w, acc[0]);  acc[1]  = fmaf(fa.y, w, acc[1]);
      acc[2]  = fmaf(fa.z, w, acc[2]);  acc[3]  = fmaf(fa.w, w, acc[3]);
      acc[4]  = fmaf(fb.x, w, acc[4]);  acc[5]  = fmaf(fb.y, w, acc[5]);
      acc[6]  = fmaf(fb.z, w, acc[6]);  acc[7]  = fmaf(fb.w, w, acc[7]);
      acc[8]  = fmaf(fc.x, w, acc[8]);  acc[9]  = fmaf(fc.y, w, acc[9]);
      acc[10] = fmaf(fc.z, w, acc[10]); acc[11] = fmaf(fc.w, w, acc[11]);
      acc[12] = fmaf(fd.x, w, acc[12]); acc[13] = fmaf(fd.y, w, acc[13]);
      acc[14] = fmaf(fd.z, w, acc[14]); acc[15] = fmaf(fd.w, w, acc[15]);
    }
  }
  __syncthreads();   // sdl ready; f reads done

  // ---- neighbor coords: nbc[v][(k-1)*2+comp] = verts + sd ----
  {
    int v = t >> 4, j = t & 15, k = (j >> 1) + 1, comp = j & 1;
    int vid = v0 + v;
    nbc[v][j] = verts[vid * 2 + comp] + sdl[v][k * 2 + comp];
  }
  __syncthreads();   // nbc ready; f free to overwrite

  // ---- neighbor slices 1..8 ----
  for (int k = 0; k < 8; ++k) {
    if constexpr (HWC) {
      GatIssue g[4];
      float gxy[4][2];
#pragma unroll
      for (int s = 0; s < 4; ++s) {
        int v = wv * 4 + s, vid = v0 + v, b = vid >> 13;
        float gx = nbc[v][k * 2], gy = nbc[v][k * 2 + 1];
        gxy[s][0] = gx; gxy[s][1] = gy;
        g[s] = gat_issue(imgp, b, gx, gy, l);
      }
#pragma unroll
      for (int s = 0; s < 4; ++s) {
        int v = wv * 4 + s;
        float4 r = gat_finish(g[s], l);
        if (l < 32) {
          f[FADDR(4 * l + 0, v)] = r.x;
          f[FADDR(4 * l + 1, v)] = r.y;
          f[FADDR(4 * l + 2, v)] = r.z;
          f[FADDR(4 * l + 3, v)] = r.w;
        }
        if (l == 32) { f[FADDR(128, v)] = gxy[s][0]; f[FADDR(129, v)] = gxy[s][1]; }
      }
    } else {
      for (int s = 0; s < 4; ++s) {
        int v = wv * 4 + s, vid = v0 + v, b = vid >> 13;
        float gx = nbc[v][k * 2], gy = nbc[v][k * 2 + 1];
        int xs, ys; float ax, ay;
        coords(gx, gy, xs, ys, ax, ay);
        f[FADDR(l, v)] = gat1_chw(imgp, b, l, xs, ys, ax, ay);
        f[FADDR(l + 64, v)] = gat1_chw(imgp, b, l + 64, xs, ys, ax, ay);
        if (l == 0) { f[FADDR(128, v)] = gx; f[FADDR(129, v)] = gy; }
      }
    }
    __syncthreads();
    const float* Ws = Wnb + (size_t)k * WSL;
    for (int e = e0; e < e0 + 65; ++e) {
      float w = Ws[e * 128 + o];
      const float4* fp = (const float4*)&f[FADDR(e, 0)];
      float4 fa = fp[0], fb = fp[1], fc = fp[2], fd = fp[3];
      acc[0]  = fmaf(fa.x, w, acc[0]);  acc[1]  = fmaf(fa.y, w, acc[1]);
      acc[2]  = fmaf(fa.z, w, acc[2]);  acc[3]  = fmaf(fa.w, w, acc[3]);
      acc[4]  = fmaf(fb.x, w, acc[4]);  acc[5]  = fmaf(fb.y, w, acc[5]);
      acc[6]  = fmaf(fb.z, w, acc[6]);  acc[7]  = fmaf(fb.w, w, acc[7]);
      acc[8]  = fmaf(fc.x, w, acc[8]);  acc[9]  = fmaf(fc.y, w, acc[9]);
      acc[10] = fmaf(fc.z, w, acc[10]); acc[11] = fmaf(fc.w, w, acc[11]);
      acc[12] = fmaf(fd.x, w, acc[12]); acc[13] = fmaf(fd.y, w, acc[13]);
      acc[14] = fmaf(fd.z, w, acc[14]); acc[15] = fmaf(fd.w, w, acc[15]);
    }
    __syncthreads();  // protect f before next gather overwrites
  }

  // ---- reduce the two e-halves and store ----
  if (hs) {
#pragma unroll
    for (int j = 0; j < VPB; ++j) red[o][j] = acc[j];
  }
  __syncthreads();
  if (!hs) {
    float bt = btot[o];
#pragma unroll
    for (int j = 0; j < VPB; ++j)
      out[(size_t)(v0 + j) * CC + o] = acc[j] + red[o][j] + bt;
  }
}

// ---------------- launch ----------------

extern "C" void kernel_launch(void* const* d_in, const int* in_sizes, int n_in,
                              void* d_out, int out_size, void* d_ws, size_t ws_size,
                              hipStream_t stream) {
  const float* img   = (const float*)d_in[0];
  const float* verts = (const float*)d_in[1];
  const float* W_sd  = (const float*)d_in[2];
  const float* b_sd  = (const float*)d_in[3];
  const float* W_d1  = (const float*)d_in[4];
  const float* b_d1  = (const float*)d_in[5];
  const float* W_d2  = (const float*)d_in[6];
  const float* b_d2  = (const float*)d_in[7];
  const float* W_sn  = (const float*)d_in[8];
  const float* b_sn  = (const float*)d_in[9];
  const float* W_c1  = (const float*)d_in[10];
  const float* b_c1  = (const float*)d_in[11];
  const float* W_c2  = (const float*)d_in[12];
  const float* b_c2  = (const float*)d_in[13];
  float* out = (float*)d_out;
  float* ws = (float*)d_ws;

  const size_t imgT_fl = (size_t)BB * HWp * CC;          // ~524 MB
  const size_t wt_fl   = 11 * (size_t)WSL + 384;         // ~734 KB
  bool hwc = ws_size >= (imgT_fl + wt_fl) * sizeof(float);

  float* base = ws;
  float* imgT = nullptr;
  if (hwc) { imgT = ws; base = ws + imgT_fl; }
  float* Wd   = base;  base += WSL;
  float* bdf  = base;  base += 128;
  float* Wcc  = base;  base += WSL;
  float* bcc  = base;  base += 128;
  float* Wcen = base;  base += WSL;
  float* Wnb  = base;  base += 8 * WSL;
  float* btot = base;

  if (hwc) transpose_k<<<dim3(HWp / 64, BB), 256, 0, stream>>>(img, imgT);
  prep1<<<256, 130, 0, stream>>>(W_d1, b_d1, W_d2, b_d2, W_c1, b_c1, W_c2, b_c2,
                                 Wd, bdf, Wcc, bcc);
  prep2<<<130, 128, 0, stream>>>(W_sn, b_sn, Wd, bdf, Wcc, bcc, Wcen, Wnb, btot);

  if (hwc) {
    fused_all<true><<<BB * NN / VPB, 256, 0, stream>>>(imgT, verts, W_sd, b_sd,
                                                       Wcen, Wnb, btot, out);
  } else {
    fused_all<false><<<BB * NN / VPB, 256, 0, stream>>>(img, verts, W_sd, b_sd,
                                                        Wcen, Wnb, btot, out);
  }
}